// Round 5
// baseline (2308.798 us; speedup 1.0000x reference)
//
#include <hip/hip_runtime.h>
#include <stdint.h>

#define MROWS  200704
#define SCALE_ 0.17677669529663687f  // 32^-0.5

typedef __attribute__((ext_vector_type(8))) short bf16x8;
typedef __attribute__((ext_vector_type(4))) float f32x4;
union V8 { uint4 u; unsigned short s[8]; };

__device__ __forceinline__ float bf2f(unsigned short u) {
  union { unsigned int i; float f; } c; c.i = ((unsigned int)u) << 16; return c.f;
}
__device__ __forceinline__ unsigned short f2bf(float f) {
  union { float f; unsigned int i; } c; c.f = f;
  unsigned int lsb = (c.i >> 16) & 1;
  return (unsigned short)((c.i + 0x7fffu + lsb) >> 16);
}
__device__ __forceinline__ uint2 pack4(float a, float b, float c, float d) {
  uint2 r;
  r.x = (unsigned)f2bf(a) | ((unsigned)f2bf(b) << 16);
  r.y = (unsigned)f2bf(c) | ((unsigned)f2bf(d) << 16);
  return r;
}
// tanh-form GELU, exp-based (~7 VALU ops); |err vs exact erf-gelu| < 1e-3
__device__ __forceinline__ float gelu_f(float x) {
  float x2 = x * x;
  float arg = x * fmaf(0.07135481f, x2, 1.59576912f);   // 2*0.7978846*(x+0.044715x^3)
  float e = __expf(arg);
  float r = __builtin_amdgcn_rcpf(1.0f + e);
  return fmaf(-x, r, x);                                // x*(1 - 1/(1+e^{2y}))
}

// ---- async global->LDS, 16B per lane ----
typedef __attribute__((address_space(1))) const void gas_t;
typedef __attribute__((address_space(3))) void las_t;
__device__ __forceinline__ void gload16(const void* g, void* l) {
  __builtin_amdgcn_global_load_lds((gas_t*)g, (las_t*)l, 16, 0, 0);
}

// ---- swizzled A-tile (128 rows x 192 bf16) helpers (qkv/proj) ----
__device__ __forceinline__ bf16x8 ard(const unsigned short* As, int row, int k) {
  return *reinterpret_cast<const bf16x8*>(As + row * 192 + (((k >> 3) ^ (row & 7)) << 3));
}
__device__ __forceinline__ void awr(unsigned short* As, int row, int c, unsigned short v) {
  As[row * 192 + (((c >> 3) ^ (row & 7)) << 3) + (c & 7)] = v;
}
template<int RS>
__device__ __forceinline__ void stage_a(const unsigned short* __restrict__ src,
                                        unsigned short* As, int wv, int lane, int colofs) {
  #pragma unroll
  for (int i = 0; i < 12; ++i) {
    int g = wv * 768 + i * 64 + lane;
    int row = g / 24, c = g - row * 24;
    int sc = c ^ (row & 7);
    gload16(src + (size_t)row * RS + colofs + sc * 8, As + (wv * 768 + i * 64) * 8);
  }
}
// LN one row (64 lanes) -> swizzled LDS bf16
__device__ __forceinline__ void ln_row(const float* __restrict__ xr,
    const float* __restrict__ g, const float* __restrict__ b,
    unsigned short* As, int row, int lane) {
  float v0 = xr[lane], v1 = xr[lane + 64], v2 = xr[lane + 128];
  float s  = v0 + v1 + v2;
  float s2 = v0*v0 + v1*v1 + v2*v2;
  #pragma unroll
  for (int m = 32; m >= 1; m >>= 1) { s += __shfl_xor(s, m); s2 += __shfl_xor(s2, m); }
  float mean = s * (1.0f/192.0f);
  float var  = s2 * (1.0f/192.0f) - mean*mean;
  float inv  = rsqrtf(var + 1e-5f);
  awr(As, row, lane,       f2bf((v0-mean)*inv*g[lane]      + b[lane]));
  awr(As, row, lane+64,    f2bf((v1-mean)*inv*g[lane+64]   + b[lane+64]));
  awr(As, row, lane+128,   f2bf((v2-mean)*inv*g[lane+128]  + b[lane+128]));
}
// SWAPPED-operand panel: acc[mi][ni] = D^T tiles -> lane holds row m=lane&15,
// 4 consecutive output cols per acc reg.
__device__ __forceinline__ void panel_mmS(const bf16x8 (&afr)[6][4],
    const unsigned short* __restrict__ Wp, int kq, f32x4 (&acc)[4][2]) {
  bf16x8 bfr[6][2];
  #pragma unroll
  for (int ks = 0; ks < 6; ++ks) {
    bfr[ks][0] = *reinterpret_cast<const bf16x8*>(Wp + ks*32 + kq);
    bfr[ks][1] = *reinterpret_cast<const bf16x8*>(Wp + 16*192 + ks*32 + kq);
  }
  #pragma unroll
  for (int ks = 0; ks < 6; ++ks)
    #pragma unroll
    for (int mi = 0; mi < 4; ++mi) {
      acc[mi][0] = __builtin_amdgcn_mfma_f32_16x16x32_bf16(bfr[ks][0], afr[ks][mi], acc[mi][0], 0, 0, 0);
      acc[mi][1] = __builtin_amdgcn_mfma_f32_16x16x32_bf16(bfr[ks][1], afr[ks][mi], acc[mi][1], 0, 0, 0);
    }
}

// ---------------- weight convert+transpose ----------------
__global__ __launch_bounds__(256) void wt_k(const float* __restrict__ W,
    unsigned short* __restrict__ Wt, int K, int N)
{
  int idx = blockIdx.x * 256 + threadIdx.x;
  if (idx < K * N) {
    int k = idx / N, n = idx - k * N;
    Wt[(size_t)n * K + k] = f2bf(W[idx]);
  }
}

// ---------------- fused LN1(windowed gather) + QKV GEMM ----------------
__global__ __launch_bounds__(256, 2) void qkv_k(const float* __restrict__ X,
    const float* __restrict__ g, const float* __restrict__ b,
    const unsigned short* __restrict__ Wt, const float* __restrict__ bias,
    unsigned short* __restrict__ C, int shift)
{
  __shared__ unsigned short As[128 * 192];
  const int tid = threadIdx.x, lane = tid & 63, wv = tid >> 6;
  const int row0 = blockIdx.x * 128;
  #pragma unroll 2
  for (int r = 0; r < 32; ++r) {
    int row = wv * 32 + r, wr = row0 + row;
    int win = wr / 49, n = wr - win * 49;
    int bi = win >> 6, w64 = win & 63, wh = w64 >> 3, ww = w64 & 7;
    int ti = n / 7, tj = n - ti * 7;
    int gh = wh*7 + ti + shift; if (gh >= 56) gh -= 56;
    int gw = ww*7 + tj + shift; if (gw >= 56) gw -= 56;
    ln_row(X + ((size_t)bi*3136 + gh*56 + gw)*192, g, b, As, row, lane);
  }
  __syncthreads();
  const int wm = wv >> 1, wn = wv & 1, l15 = lane & 15, kq = (lane >> 4) * 8, qd = lane >> 4;
  bf16x8 afr[6][4];
  #pragma unroll
  for (int ks = 0; ks < 6; ++ks)
    #pragma unroll
    for (int mi = 0; mi < 4; ++mi)
      afr[ks][mi] = ard(As, wm*64 + mi*16 + l15, ks*32 + kq);
  #pragma unroll 2
  for (int p = 0; p < 9; ++p) {
    f32x4 acc[4][2] = {};
    panel_mmS(afr, Wt + (size_t)(p*64 + wn*32 + l15) * 192, kq, acc);
    #pragma unroll
    for (int mi = 0; mi < 4; ++mi)
    #pragma unroll
    for (int ni = 0; ni < 2; ++ni) {
      int row = row0 + wm*64 + mi*16 + l15;
      int col = p*64 + wn*32 + ni*16 + qd*4;
      float4 bv = *reinterpret_cast<const float4*>(bias + col);
      uint2 pk = pack4(acc[mi][ni][0]+bv.x, acc[mi][ni][1]+bv.y,
                       acc[mi][ni][2]+bv.z, acc[mi][ni][3]+bv.w);
      *reinterpret_cast<uint2*>(C + (size_t)row * 576 + col) = pk;
    }
  }
}

// ---------------- proj GEMM + window-reverse scatter residual ----------------
__global__ __launch_bounds__(256, 2) void proj_k(const unsigned short* __restrict__ A,
    const unsigned short* __restrict__ Wt, const float* __restrict__ bias,
    const float* __restrict__ Xres, float* __restrict__ Xdst, int shift)
{
  __shared__ unsigned short As[128 * 192];
  const int tid = threadIdx.x, lane = tid & 63, wv = tid >> 6;
  const int row0 = blockIdx.x * 128;
  stage_a<192>(A + (size_t)row0 * 192, As, wv, lane, 0);
  __syncthreads();
  const int wm = wv >> 1, wn = wv & 1, l15 = lane & 15, kq = (lane >> 4) * 8, qd = lane >> 4;
  bf16x8 afr[6][4];
  #pragma unroll
  for (int ks = 0; ks < 6; ++ks)
    #pragma unroll
    for (int mi = 0; mi < 4; ++mi)
      afr[ks][mi] = ard(As, wm*64 + mi*16 + l15, ks*32 + kq);
  // per-lane scatter row bases (lane&15 fixes the row within each 16-tile)
  int rbase[4];
  #pragma unroll
  for (int mi = 0; mi < 4; ++mi) {
    int gr = row0 + wm*64 + mi*16 + l15;
    int win = gr / 49, n = gr - win * 49;
    int bi = win >> 6, w64 = win & 63, wh = w64 >> 3, ww = w64 & 7;
    int ti = n / 7, tj = n - ti * 7;
    int gh = wh*7 + ti + shift; if (gh >= 56) gh -= 56;
    int gw = ww*7 + tj + shift; if (gw >= 56) gw -= 56;
    rbase[mi] = (bi*3136 + gh*56 + gw) * 192;
  }
  #pragma unroll
  for (int p = 0; p < 3; ++p) {
    f32x4 acc[4][2] = {};
    panel_mmS(afr, Wt + (size_t)(p*64 + wn*32 + l15) * 192, kq, acc);
    #pragma unroll
    for (int mi = 0; mi < 4; ++mi)
    #pragma unroll
    for (int ni = 0; ni < 2; ++ni) {
      int col = p*64 + wn*32 + ni*16 + qd*4;
      float4 bv = *reinterpret_cast<const float4*>(bias + col);
      size_t idx = (size_t)rbase[mi] + col;
      float4 xr = *reinterpret_cast<const float4*>(Xres + idx);
      float4 o;
      o.x = xr.x + acc[mi][ni][0] + bv.x; o.y = xr.y + acc[mi][ni][1] + bv.y;
      o.z = xr.z + acc[mi][ni][2] + bv.z; o.w = xr.w + acc[mi][ni][3] + bv.w;
      *reinterpret_cast<float4*>(Xdst + idx) = o;
    }
  }
}

// ---------------- fused LN2 + FC1 + GELU + FC2 + residual ----------------
// 64 rows / 4 waves (2x2). A-frags hoisted to regs; same LDS arena holds LN'd A,
// then each 192-wide H quarter. All MFMA swapped-operand.
__global__ __launch_bounds__(256, 2) void mlp_k(
    const float* __restrict__ X,
    const float* __restrict__ g, const float* __restrict__ b,
    const unsigned short* __restrict__ W1t, // [768][192]
    const float* __restrict__ b1,
    const unsigned short* __restrict__ W2t, // [192][768]
    const float* __restrict__ b2,
    float* __restrict__ Y)
{
  __shared__ unsigned short Hs[64][200];    // LN'd A (cols 0..191), then H quarters
  const int row0 = blockIdx.x * 64;
  const int tid = threadIdx.x, lane = tid & 63, wv = tid >> 6;
  const int l15 = lane & 15, qd = lane >> 4, kq = qd * 8;
  const int wm = wv >> 1, wn = wv & 1;
  // ---- LN2: wave wv -> rows wv*16 .. +15
  #pragma unroll 2
  for (int r = 0; r < 16; ++r) {
    int row = wv * 16 + r;
    const float* xr = X + (size_t)(row0 + row) * 192;
    float v0 = xr[lane], v1 = xr[lane + 64], v2 = xr[lane + 128];
    float s  = v0 + v1 + v2;
    float s2 = v0*v0 + v1*v1 + v2*v2;
    #pragma unroll
    for (int m = 32; m >= 1; m >>= 1) { s += __shfl_xor(s, m); s2 += __shfl_xor(s2, m); }
    float mean = s * (1.0f/192.0f);
    float var  = s2 * (1.0f/192.0f) - mean*mean;
    float inv  = rsqrtf(var + 1e-5f);
    Hs[row][lane]     = f2bf((v0-mean)*inv*g[lane]      + b[lane]);
    Hs[row][lane+64]  = f2bf((v1-mean)*inv*g[lane+64]   + b[lane+64]);
    Hs[row][lane+128] = f2bf((v2-mean)*inv*g[lane+128]  + b[lane+128]);
  }
  __syncthreads();
  // ---- hoist A-frags (rows wm*32 .. +31)
  bf16x8 afr[6][2];
  #pragma unroll
  for (int ks = 0; ks < 6; ++ks)
    #pragma unroll
    for (int mt = 0; mt < 2; ++mt)
      afr[ks][mt] = *reinterpret_cast<const bf16x8*>(&Hs[wm*32 + mt*16 + l15][ks*32 + kq]);
  f32x4 acc2[6][2] = {};
  #pragma unroll 1
  for (int q = 0; q < 4; ++q) {
    // ---- FC1: this wave: h-cols q*192 + wn*96 .. +95, rows wm*32..+31
    f32x4 acc1[6][2] = {};
    #pragma unroll
    for (int ks = 0; ks < 6; ++ks) {
      bf16x8 w1f[6];
      #pragma unroll
      for (int ht = 0; ht < 6; ++ht)
        w1f[ht] = *reinterpret_cast<const bf16x8*>(
            &W1t[(size_t)(q*192 + wn*96 + ht*16 + l15) * 192 + ks*32 + kq]);
      #pragma unroll
      for (int ht = 0; ht < 6; ++ht)
        #pragma unroll
        for (int mt = 0; mt < 2; ++mt)
          acc1[ht][mt] = __builtin_amdgcn_mfma_f32_16x16x32_bf16(w1f[ht], afr[ks][mt], acc1[ht][mt], 0, 0, 0);
    }
    __syncthreads();   // all waves done reading Hs (prev FC2 / afr hoist)
    // ---- GELU -> Hs quarter (4 consecutive h per acc reg -> 8B writes)
    #pragma unroll
    for (int ht = 0; ht < 6; ++ht) {
      float4 bv = *reinterpret_cast<const float4*>(b1 + q*192 + wn*96 + ht*16 + qd*4);
      #pragma unroll
      for (int mt = 0; mt < 2; ++mt) {
        uint2 pk = pack4(gelu_f(acc1[ht][mt][0]+bv.x), gelu_f(acc1[ht][mt][1]+bv.y),
                         gelu_f(acc1[ht][mt][2]+bv.z), gelu_f(acc1[ht][mt][3]+bv.w));
        *reinterpret_cast<uint2*>(&Hs[wm*32 + mt*16 + l15][wn*96 + ht*16 + qd*4]) = pk;
      }
    }
    __syncthreads();   // Hs quarter ready
    // ---- FC2 partial over this quarter's 192 h's
    #pragma unroll
    for (int ks = 0; ks < 6; ++ks) {
      bf16x8 hbf[2];
      #pragma unroll
      for (int mt = 0; mt < 2; ++mt)
        hbf[mt] = *reinterpret_cast<const bf16x8*>(&Hs[wm*32 + mt*16 + l15][ks*32 + kq]);
      #pragma unroll
      for (int ct = 0; ct < 6; ++ct) {
        bf16x8 w2f = *reinterpret_cast<const bf16x8*>(
            &W2t[(size_t)(wn*96 + ct*16 + l15) * 768 + q*192 + ks*32 + kq]);
        #pragma unroll
        for (int mt = 0; mt < 2; ++mt)
          acc2[ct][mt] = __builtin_amdgcn_mfma_f32_16x16x32_bf16(w2f, hbf[mt], acc2[ct][mt], 0, 0, 0);
      }
    }
  }
  // ---- epilogue: bias + residual, float4
  #pragma unroll
  for (int ct = 0; ct < 6; ++ct) {
    int col = wn*96 + ct*16 + qd*4;
    float4 bv = *reinterpret_cast<const float4*>(b2 + col);
    #pragma unroll
    for (int mt = 0; mt < 2; ++mt) {
      size_t idx = (size_t)(row0 + wm*32 + mt*16 + l15) * 192 + col;
      float4 xr = *reinterpret_cast<const float4*>(X + idx);
      float4 o;
      o.x = xr.x + acc2[ct][mt][0] + bv.x; o.y = xr.y + acc2[ct][mt][1] + bv.y;
      o.z = xr.z + acc2[ct][mt][2] + bv.z; o.w = xr.w + acc2[ct][mt][3] + bv.w;
      *reinterpret_cast<float4*>(Y + idx) = o;
    }
  }
}

// ---------------- Windowed attention: one wave per (window, head) ----------------
template<bool SHIFTED>
__global__ __launch_bounds__(64) void attn_k(
    const unsigned short* __restrict__ qkv,
    const float* __restrict__ rpb,
    unsigned short* __restrict__ out)
{
  __shared__ float kv[2][49][32];
  int blk = blockIdx.x;
  int win = blk / 6, h = blk - win * 6;
  int lane = threadIdx.x;
  const unsigned short* base = qkv + (size_t)win * 49 * 576;
  for (int idx = lane; idx < 196; idx += 64) {
    int n = idx >> 2, sg = (idx & 3) * 8;
    V8 kk, vv;
    kk.u = *reinterpret_cast<const uint4*>(base + n*576 + 192 + h*32 + sg);
    vv.u = *reinterpret_cast<const uint4*>(base + n*576 + 384 + h*32 + sg);
    #pragma unroll
    for (int j = 0; j < 8; ++j) { kv[0][n][sg+j] = bf2f(kk.s[j]); kv[1][n][sg+j] = bf2f(vv.s[j]); }
  }
  __syncthreads();
  if (lane < 49) {
    float q[32];
    const unsigned short* qr = base + (size_t)lane * 576 + h * 32;
    #pragma unroll
    for (int sg = 0; sg < 4; ++sg) {
      V8 qq; qq.u = *reinterpret_cast<const uint4*>(qr + sg*8);
      #pragma unroll
      for (int j = 0; j < 8; ++j) q[sg*8+j] = bf2f(qq.s[j]) * SCALE_;
    }
    int ti = lane / 7, tj = lane - ti * 7;
    int wi = win & 63, wh = wi >> 3, ww = wi & 7;
    int rid = 0;
    if (SHIFTED) {
      int hh = wh*7 + ti, wg = ww*7 + tj;
      rid = (hh < 49 ? 0 : (hh < 53 ? 1 : 2)) * 3 + (wg < 49 ? 0 : (wg < 53 ? 1 : 2));
    }
    float s[49];
    float mx = -1e30f;
    #pragma unroll
    for (int m = 0; m < 49; ++m) {
      float a = 0.f;
      #pragma unroll
      for (int d4 = 0; d4 < 8; ++d4) {
        float4 kf = *reinterpret_cast<const float4*>(&kv[0][m][d4*4]);
        a += q[d4*4+0]*kf.x + q[d4*4+1]*kf.y + q[d4*4+2]*kf.z + q[d4*4+3]*kf.w;
      }
      int mi = m / 7, mj = m - mi * 7;
      a += rpb[((ti - mi + 6) * 13 + (tj - mj + 6)) * 6 + h];
      if (SHIFTED) {
        int hh = wh*7 + mi, wg = ww*7 + mj;
        int rid2 = (hh < 49 ? 0 : (hh < 53 ? 1 : 2)) * 3 + (wg < 49 ? 0 : (wg < 53 ? 1 : 2));
        if (rid2 != rid) a -= 100.f;
      }
      s[m] = a;
      mx = fmaxf(mx, a);
    }
    float sum = 0.f;
    #pragma unroll
    for (int m = 0; m < 49; ++m) { float e = __expf(s[m] - mx); s[m] = e; sum += e; }
    float rs = 1.f / sum;
    float o[32];
    #pragma unroll
    for (int d = 0; d < 32; ++d) o[d] = 0.f;
    #pragma unroll
    for (int m = 0; m < 49; ++m) {
      float p = s[m] * rs;
      #pragma unroll
      for (int d4 = 0; d4 < 8; ++d4) {
        float4 vf = *reinterpret_cast<const float4*>(&kv[1][m][d4*4]);
        o[d4*4+0] += p*vf.x; o[d4*4+1] += p*vf.y; o[d4*4+2] += p*vf.z; o[d4*4+3] += p*vf.w;
      }
    }
    unsigned short* orow = out + ((size_t)win * 49 + lane) * 192 + h * 32;
    #pragma unroll
    for (int sg = 0; sg < 4; ++sg) {
      V8 pk;
      #pragma unroll
      for (int j = 0; j < 8; ++j) pk.s[j] = f2bf(o[sg*8+j]);
      *reinterpret_cast<uint4*>(orow + sg*8) = pk.u;
    }
  }
}

// ---------------- launch ----------------
extern "C" void kernel_launch(void* const* d_in, const int* in_sizes, int n_in,
                              void* d_out, int out_size, void* d_ws, size_t ws_size,
                              hipStream_t stream) {
  const float* x    = (const float*)d_in[0];
  const float* n1g  = (const float*)d_in[1];
  const float* n1b  = (const float*)d_in[2];
  const float* qkvw = (const float*)d_in[3];
  const float* qkvb = (const float*)d_in[4];
  const float* rpb  = (const float*)d_in[5];
  const float* pw   = (const float*)d_in[6];
  const float* pb   = (const float*)d_in[7];
  const float* n2g  = (const float*)d_in[8];
  const float* n2b  = (const float*)d_in[9];
  const float* f1w  = (const float*)d_in[10];
  const float* f1b  = (const float*)d_in[11];
  const float* f2w  = (const float*)d_in[12];
  const float* f2b  = (const float*)d_in[13];
  float* out = (float*)d_out;

  const size_t XBYTES = (size_t)MROWS * 192 * 4;
  const size_t QBYTES = (size_t)MROWS * 576 * 2;
  const size_t ABYTES = (size_t)MROWS * 192 * 2;
  char* ws = (char*)d_ws;
  float* x1 = (float*)ws;
  unsigned short* Bbuf = (unsigned short*)(ws + XBYTES);
  unsigned short* Abuf = (unsigned short*)(ws + XBYTES + QBYTES);
  unsigned short* WT   = (unsigned short*)(ws + XBYTES + QBYTES + ABYTES);
  const size_t WQ = 110592, WP = 36864, W1 = 147456, W2 = 147456;
  const size_t WD = WQ + WP + W1 + W2;

  for (int d = 0; d < 2; ++d) {
    unsigned short* wt = WT + d * WD;
    wt_k<<<(int)((WQ + 255)/256), 256, 0, stream>>>(qkvw + (size_t)d*WQ, wt,                 192, 576);
    wt_k<<<(int)((WP + 255)/256), 256, 0, stream>>>(pw   + (size_t)d*WP, wt + WQ,            192, 192);
    wt_k<<<(int)((W1 + 255)/256), 256, 0, stream>>>(f1w  + (size_t)d*W1, wt + WQ + WP,       192, 768);
    wt_k<<<(int)((W2 + 255)/256), 256, 0, stream>>>(f2w  + (size_t)d*W2, wt + WQ + WP + W1,  768, 192);
  }

  const int GB = MROWS / 128;   // 1568

  for (int i = 0; i < 2; ++i) {
    int shift = i ? 3 : 0;
    const float* xin = i ? (const float*)x1 : x;
    float* xfin = i ? out : x1;
    const unsigned short* wt = WT + i * WD;
    // 1. LN1 + gather + QKV gemm -> Bbuf
    qkv_k<<<GB, 256, 0, stream>>>(xin, n1g + i*192, n1b + i*192, wt, qkvb + i*576, Bbuf, shift);
    // 2. attention -> Abuf
    if (shift) attn_k<true ><<<4096*6, 64, 0, stream>>>(Bbuf, rpb + i*169*6, Abuf);
    else       attn_k<false><<<4096*6, 64, 0, stream>>>(Bbuf, rpb + i*169*6, Abuf);
    // 3. proj gemm + window-reverse scatter residual -> x1
    proj_k<<<GB, 256, 0, stream>>>(Abuf, wt + WQ, pb + i*192, xin, x1, shift);
    // 4. fused LN2 + FC1 + GELU + FC2 + residual -> x1 / out
    mlp_k<<<MROWS/64, 256, 0, stream>>>(x1, n2g + i*192, n2b + i*192,
                                        wt + WQ + WP, f1b + i*768,
                                        wt + WQ + WP + W1, f2b + i*192, xfin);
  }
}

// Round 7
// 1828.139 us; speedup vs baseline: 1.2629x; 1.2629x over previous
//
#include <hip/hip_runtime.h>
#include <stdint.h>

#define MROWS  200704
#define SCALE_ 0.17677669529663687f  // 32^-0.5

typedef __attribute__((ext_vector_type(8))) short bf16x8;
typedef __attribute__((ext_vector_type(4))) float f32x4;
union V8 { uint4 u; unsigned short s[8]; };

__device__ __forceinline__ float bf2f(unsigned short u) {
  union { unsigned int i; float f; } c; c.i = ((unsigned int)u) << 16; return c.f;
}
__device__ __forceinline__ unsigned short f2bf(float f) {
  union { float f; unsigned int i; } c; c.f = f;
  unsigned int lsb = (c.i >> 16) & 1;
  return (unsigned short)((c.i + 0x7fffu + lsb) >> 16);
}
// tanh-form GELU, exp-based (~7 VALU ops); validated round 5 (absmax unchanged)
__device__ __forceinline__ float gelu_f(float x) {
  float x2 = x * x;
  float arg = x * fmaf(0.07135481f, x2, 1.59576912f);
  float e = __expf(arg);
  float r = __builtin_amdgcn_rcpf(1.0f + e);
  return fmaf(-x, r, x);
}

// ---------------- weight convert+transpose: W (K x N fp32) -> Wt (N x K bf16) ----------------
__global__ __launch_bounds__(256) void wt_k(const float* __restrict__ W,
    unsigned short* __restrict__ Wt, int K, int N)
{
  int idx = blockIdx.x * 256 + threadIdx.x;
  if (idx < K * N) {
    int k = idx / N, n = idx - k * N;
    Wt[(size_t)n * K + k] = f2bf(W[idx]);
  }
}

// ---------------- LayerNorm + shifted window partition ----------------
__global__ __launch_bounds__(256) void ln_k(const float* __restrict__ X,
    const float* __restrict__ g, const float* __restrict__ b,
    unsigned short* __restrict__ out, int shift)
{
  int wr = blockIdx.x * 4 + (threadIdx.x >> 6);
  int lane = threadIdx.x & 63;
  int win = wr / 49, n = wr % 49;
  int bi = win >> 6, w64 = win & 63;
  int wh = w64 >> 3, ww = w64 & 7;
  int ti = n / 7, tj = n % 7;
  int gh = wh * 7 + ti + shift; if (gh >= 56) gh -= 56;
  int gw = ww * 7 + tj + shift; if (gw >= 56) gw -= 56;
  size_t srow = (size_t)bi * 3136 + gh * 56 + gw;
  const float* xr = X + srow * 192;
  float v0 = xr[lane], v1 = xr[lane + 64], v2 = xr[lane + 128];
  float s  = v0 + v1 + v2;
  float s2 = v0*v0 + v1*v1 + v2*v2;
  #pragma unroll
  for (int m = 32; m >= 1; m >>= 1) { s += __shfl_xor(s, m); s2 += __shfl_xor(s2, m); }
  float mean = s * (1.0f/192.0f);
  float var  = s2 * (1.0f/192.0f) - mean*mean;
  float inv  = rsqrtf(var + 1e-5f);
  unsigned short* orow = out + (size_t)wr * 192;
  orow[lane]       = f2bf((v0-mean)*inv*g[lane]      + b[lane]);
  orow[lane+64]    = f2bf((v1-mean)*inv*g[lane+64]   + b[lane+64]);
  orow[lane+128]   = f2bf((v2-mean)*inv*g[lane+128]  + b[lane+128]);
}

// ---------------- MFMA GEMM (K=192): A (bf16 LDS-staged) x Wt (bf16 direct global) ----------------
// B fragments fully preloaded before the k-loop (outside barriers); A-stage regs double-buffered.
// EPI: 0 = write bf16 (qkv); 1 = proj: window-reverse scatter + residual (N==192)
template<int EPI>
__global__ __launch_bounds__(256, 4) void gemm2_k(
    const unsigned short* __restrict__ A,
    const unsigned short* __restrict__ Wt,   // [N][192] bf16
    const float* __restrict__ bias,
    unsigned short* __restrict__ Cbf,
    const float* __restrict__ Xres,
    float* __restrict__ Xdst,
    int N, int shift)
{
  __shared__ unsigned short As[128][40];   // pad 40: 2-way banked reads (free)
  const int tid = threadIdx.x;
  const int lane = tid & 63, wv = tid >> 6;
  const int wm = wv >> 1, wn = wv & 1;     // 2x2 waves over 128x64 tile
  const int row0 = blockIdx.x * 128;
  const int n0   = blockIdx.y * 64;
  const int fr = lane & 15, kq = (lane >> 4) * 8;
  bf16x8 bfr[6][2];
  #pragma unroll
  for (int ks = 0; ks < 6; ++ks)
    #pragma unroll
    for (int ni = 0; ni < 2; ++ni)
      bfr[ks][ni] = *reinterpret_cast<const bf16x8*>(
          &Wt[(size_t)(n0 + wn*32 + ni*16 + fr) * 192 + ks*32 + kq]);
  const int sr  = tid >> 1, ssg = (tid & 1) * 16;
  const unsigned short* arow = A + (size_t)(row0 + sr) * 192 + ssg;
  uint4 a0 = *reinterpret_cast<const uint4*>(arow);
  uint4 a1 = *reinterpret_cast<const uint4*>(arow + 8);
  f32x4 acc[4][2] = {};
  #pragma unroll
  for (int ks = 0; ks < 6; ++ks) {
    __syncthreads();
    *reinterpret_cast<uint4*>(&As[sr][ssg])     = a0;
    *reinterpret_cast<uint4*>(&As[sr][ssg + 8]) = a1;
    if (ks < 5) {
      a0 = *reinterpret_cast<const uint4*>(arow + (ks+1)*32);
      a1 = *reinterpret_cast<const uint4*>(arow + (ks+1)*32 + 8);
    }
    __syncthreads();
    #pragma unroll
    for (int mi = 0; mi < 4; ++mi) {
      bf16x8 afr = *reinterpret_cast<const bf16x8*>(&As[wm*64 + mi*16 + fr][kq]);
      #pragma unroll
      for (int ni = 0; ni < 2; ++ni)
        acc[mi][ni] = __builtin_amdgcn_mfma_f32_16x16x32_bf16(afr, bfr[ks][ni], acc[mi][ni], 0, 0, 0);
    }
  }
  const int lcol = lane & 15, lr4 = (lane >> 4) * 4;
  #pragma unroll
  for (int mi = 0; mi < 4; ++mi)
  #pragma unroll
  for (int ni = 0; ni < 2; ++ni)
  #pragma unroll
  for (int i = 0; i < 4; ++i) {
    int gr = row0 + wm*64 + mi*16 + lr4 + i;
    int gc = n0 + wn*32 + ni*16 + lcol;
    float v = acc[mi][ni][i] + bias[gc];
    if (EPI == 0) {
      Cbf[(size_t)gr * N + gc] = f2bf(v);
    } else {
      int win = gr / 49, n = gr % 49;
      int bi = win >> 6, w64 = win & 63;
      int wh = w64 >> 3, ww = w64 & 7;
      int ti = n / 7, tj = n % 7;
      int gh = wh*7 + ti + shift; if (gh >= 56) gh -= 56;
      int gw = ww*7 + tj + shift; if (gw >= 56) gw -= 56;
      size_t idx = ((size_t)bi * 3136 + gh * 56 + gw) * 192 + gc;
      Xdst[idx] = Xres[idx] + v;
    }
  }
}

// ---------------- Fused LN2 + FC1 + GELU + FC2 + residual (round-2 structure, verbatim) ----------------
// 64 rows per block, 512 threads (8 waves). FC1 (64x768) in two 384-col halves
// staged in LDS; FC2 accumulates across halves with 12-step inline-load k-loop.
// Only change vs round 2: erff-GELU -> gelu_f.
__global__ __launch_bounds__(512, 4) void mlp_k(
    const float* __restrict__ X,
    const float* __restrict__ g, const float* __restrict__ b,
    const unsigned short* __restrict__ W1t, // [768][192] bf16
    const float* __restrict__ b1,
    const unsigned short* __restrict__ W2t, // [192][768] bf16
    const float* __restrict__ b2,
    float* __restrict__ Y)
{
  __shared__ unsigned short As[64][200];
  __shared__ unsigned short Hs[64][396];
  const int row0 = blockIdx.x * 64;
  const int tid = threadIdx.x, lane = tid & 63, wv = tid >> 6;
  #pragma unroll
  for (int r = 0; r < 8; ++r) {
    int row = wv * 8 + r;
    const float* xr = X + (size_t)(row0 + row) * 192;
    float v0 = xr[lane], v1 = xr[lane + 64], v2 = xr[lane + 128];
    float s  = v0 + v1 + v2;
    float s2 = v0*v0 + v1*v1 + v2*v2;
    #pragma unroll
    for (int m = 32; m >= 1; m >>= 1) { s += __shfl_xor(s, m); s2 += __shfl_xor(s2, m); }
    float mean = s * (1.0f/192.0f);
    float var  = s2 * (1.0f/192.0f) - mean*mean;
    float inv  = rsqrtf(var + 1e-5f);
    As[row][lane]       = f2bf((v0-mean)*inv*g[lane]      + b[lane]);
    As[row][lane+64]    = f2bf((v1-mean)*inv*g[lane+64]   + b[lane+64]);
    As[row][lane+128]   = f2bf((v2-mean)*inv*g[lane+128]  + b[lane+128]);
  }
  __syncthreads();
  const int fr = lane & 15, kq = (lane >> 4) * 8;
  const int lcol = lane & 15, lr4 = (lane >> 4) * 4;
  const int wm2 = wv >> 2, wn2 = wv & 3;    // FC2 wave grid: 2 x 4
  f32x4 acc2[2][3] = {};
  for (int hh = 0; hh < 2; ++hh) {
    f32x4 acc1[4][3] = {};
    const int c0 = hh * 384 + wv * 48;
    #pragma unroll
    for (int k0 = 0; k0 < 192; k0 += 32) {
      bf16x8 bfr[3];
      #pragma unroll
      for (int ni = 0; ni < 3; ++ni)
        bfr[ni] = *reinterpret_cast<const bf16x8*>(&W1t[(size_t)(c0 + ni*16 + fr) * 192 + k0 + kq]);
      #pragma unroll
      for (int mi = 0; mi < 4; ++mi) {
        bf16x8 afr = *reinterpret_cast<const bf16x8*>(&As[mi*16 + fr][k0 + kq]);
        #pragma unroll
        for (int ni = 0; ni < 3; ++ni)
          acc1[mi][ni] = __builtin_amdgcn_mfma_f32_16x16x32_bf16(afr, bfr[ni], acc1[mi][ni], 0, 0, 0);
      }
    }
    __syncthreads();   // previous half's FC2 finished reading Hs
    #pragma unroll
    for (int mi = 0; mi < 4; ++mi)
    #pragma unroll
    for (int ni = 0; ni < 3; ++ni)
    #pragma unroll
    for (int i = 0; i < 4; ++i) {
      int rr = mi*16 + lr4 + i;
      int cc = wv*48 + ni*16 + lcol;
      float v = acc1[mi][ni][i] + b1[hh*384 + cc];
      Hs[rr][cc] = f2bf(gelu_f(v));
    }
    __syncthreads();   // Hs ready
    #pragma unroll
    for (int k0 = 0; k0 < 384; k0 += 32) {
      bf16x8 bfr[3];
      #pragma unroll
      for (int ni = 0; ni < 3; ++ni)
        bfr[ni] = *reinterpret_cast<const bf16x8*>(
            &W2t[(size_t)(wn2*48 + ni*16 + fr) * 768 + hh*384 + k0 + kq]);
      #pragma unroll
      for (int mi = 0; mi < 2; ++mi) {
        bf16x8 afr = *reinterpret_cast<const bf16x8*>(&Hs[wm2*32 + mi*16 + fr][k0 + kq]);
        #pragma unroll
        for (int ni = 0; ni < 3; ++ni)
          acc2[mi][ni] = __builtin_amdgcn_mfma_f32_16x16x32_bf16(afr, bfr[ni], acc2[mi][ni], 0, 0, 0);
      }
    }
  }
  #pragma unroll
  for (int mi = 0; mi < 2; ++mi)
  #pragma unroll
  for (int ni = 0; ni < 3; ++ni)
  #pragma unroll
  for (int i = 0; i < 4; ++i) {
    int grow = row0 + wm2*32 + mi*16 + lr4 + i;
    int gc = wn2*48 + ni*16 + lcol;
    float v = acc2[mi][ni][i] + b2[gc];
    size_t idx = (size_t)grow * 192 + gc;
    Y[idx] = X[idx] + v;
  }
}

// ---------------- Windowed attention: one wave per (window, head) ----------------
template<bool SHIFTED>
__global__ __launch_bounds__(64) void attn_k(
    const unsigned short* __restrict__ qkv,
    const float* __restrict__ rpb,
    unsigned short* __restrict__ out)
{
  __shared__ float kv[2][49][32];
  int blk = blockIdx.x;
  int win = blk / 6, h = blk - win * 6;
  int lane = threadIdx.x;
  const unsigned short* base = qkv + (size_t)win * 49 * 576;
  for (int idx = lane; idx < 196; idx += 64) {
    int n = idx >> 2, sg = (idx & 3) * 8;
    V8 kk, vv;
    kk.u = *reinterpret_cast<const uint4*>(base + n*576 + 192 + h*32 + sg);
    vv.u = *reinterpret_cast<const uint4*>(base + n*576 + 384 + h*32 + sg);
    #pragma unroll
    for (int j = 0; j < 8; ++j) { kv[0][n][sg+j] = bf2f(kk.s[j]); kv[1][n][sg+j] = bf2f(vv.s[j]); }
  }
  __syncthreads();
  if (lane < 49) {
    float q[32];
    const unsigned short* qr = base + (size_t)lane * 576 + h * 32;
    #pragma unroll
    for (int sg = 0; sg < 4; ++sg) {
      V8 qq; qq.u = *reinterpret_cast<const uint4*>(qr + sg*8);
      #pragma unroll
      for (int j = 0; j < 8; ++j) q[sg*8+j] = bf2f(qq.s[j]) * SCALE_;
    }
    int ti = lane / 7, tj = lane - ti * 7;
    int wi = win & 63, wh = wi >> 3, ww = wi & 7;
    int rid = 0;
    if (SHIFTED) {
      int hh = wh*7 + ti, wg = ww*7 + tj;
      rid = (hh < 49 ? 0 : (hh < 53 ? 1 : 2)) * 3 + (wg < 49 ? 0 : (wg < 53 ? 1 : 2));
    }
    float s[49];
    float mx = -1e30f;
    #pragma unroll
    for (int m = 0; m < 49; ++m) {
      float a = 0.f;
      #pragma unroll
      for (int d4 = 0; d4 < 8; ++d4) {
        float4 kf = *reinterpret_cast<const float4*>(&kv[0][m][d4*4]);
        a += q[d4*4+0]*kf.x + q[d4*4+1]*kf.y + q[d4*4+2]*kf.z + q[d4*4+3]*kf.w;
      }
      int mi = m / 7, mj = m - mi * 7;
      a += rpb[((ti - mi + 6) * 13 + (tj - mj + 6)) * 6 + h];
      if (SHIFTED) {
        int hh = wh*7 + mi, wg = ww*7 + mj;
        int rid2 = (hh < 49 ? 0 : (hh < 53 ? 1 : 2)) * 3 + (wg < 49 ? 0 : (wg < 53 ? 1 : 2));
        if (rid2 != rid) a -= 100.f;
      }
      s[m] = a;
      mx = fmaxf(mx, a);
    }
    float sum = 0.f;
    #pragma unroll
    for (int m = 0; m < 49; ++m) { float e = __expf(s[m] - mx); s[m] = e; sum += e; }
    float rs = 1.f / sum;
    float o[32];
    #pragma unroll
    for (int d = 0; d < 32; ++d) o[d] = 0.f;
    #pragma unroll
    for (int m = 0; m < 49; ++m) {
      float p = s[m] * rs;
      #pragma unroll
      for (int d4 = 0; d4 < 8; ++d4) {
        float4 vf = *reinterpret_cast<const float4*>(&kv[1][m][d4*4]);
        o[d4*4+0] += p*vf.x; o[d4*4+1] += p*vf.y; o[d4*4+2] += p*vf.z; o[d4*4+3] += p*vf.w;
      }
    }
    unsigned short* orow = out + ((size_t)win * 49 + lane) * 192 + h * 32;
    #pragma unroll
    for (int sg = 0; sg < 4; ++sg) {
      V8 pk;
      #pragma unroll
      for (int j = 0; j < 8; ++j) pk.s[j] = f2bf(o[sg*8+j]);
      *reinterpret_cast<uint4*>(orow + sg*8) = pk.u;
    }
  }
}

// ---------------- launch ----------------
extern "C" void kernel_launch(void* const* d_in, const int* in_sizes, int n_in,
                              void* d_out, int out_size, void* d_ws, size_t ws_size,
                              hipStream_t stream) {
  const float* x    = (const float*)d_in[0];
  const float* n1g  = (const float*)d_in[1];
  const float* n1b  = (const float*)d_in[2];
  const float* qkvw = (const float*)d_in[3];
  const float* qkvb = (const float*)d_in[4];
  const float* rpb  = (const float*)d_in[5];
  const float* pw   = (const float*)d_in[6];
  const float* pb   = (const float*)d_in[7];
  const float* n2g  = (const float*)d_in[8];
  const float* n2b  = (const float*)d_in[9];
  const float* f1w  = (const float*)d_in[10];
  const float* f1b  = (const float*)d_in[11];
  const float* f2w  = (const float*)d_in[12];
  const float* f2b  = (const float*)d_in[13];
  float* out = (float*)d_out;

  const size_t XBYTES = (size_t)MROWS * 192 * 4;
  const size_t ABYTES = (size_t)MROWS * 192 * 2;
  const size_t QBYTES = (size_t)MROWS * 576 * 2;
  char* ws = (char*)d_ws;
  float* x1 = (float*)ws;
  unsigned short* Abuf = (unsigned short*)(ws + XBYTES);
  unsigned short* Bbuf = (unsigned short*)(ws + XBYTES + ABYTES);
  unsigned short* WT   = (unsigned short*)(ws + XBYTES + ABYTES + QBYTES);
  const size_t WQ = 110592, WP = 36864, W1 = 147456, W2 = 147456;
  const size_t WD = WQ + WP + W1 + W2;

  for (int d = 0; d < 2; ++d) {
    unsigned short* wt = WT + d * WD;
    wt_k<<<(int)((WQ + 255)/256), 256, 0, stream>>>(qkvw + (size_t)d*WQ, wt,                 192, 576);
    wt_k<<<(int)((WP + 255)/256), 256, 0, stream>>>(pw   + (size_t)d*WP, wt + WQ,            192, 192);
    wt_k<<<(int)((W1 + 255)/256), 256, 0, stream>>>(f1w  + (size_t)d*W1, wt + WQ + WP,       192, 768);
    wt_k<<<(int)((W2 + 255)/256), 256, 0, stream>>>(f2w  + (size_t)d*W2, wt + WQ + WP + W1,  768, 192);
  }

  const int LNBLK = MROWS / 4;
  const dim3 G_QKV(MROWS/128, 9), G_P(MROWS/128, 3);

  for (int i = 0; i < 2; ++i) {
    int shift = i ? 3 : 0;
    const float* xin = i ? (const float*)x1 : x;
    float* xfin = i ? out : x1;
    const unsigned short* wt = WT + i * WD;
    // 1. LN1 + shifted window partition -> Abuf
    ln_k<<<LNBLK, 256, 0, stream>>>(xin, n1g + i*192, n1b + i*192, Abuf, shift);
    // 2. QKV gemm -> Bbuf
    gemm2_k<0><<<G_QKV, 256, 0, stream>>>(Abuf, wt, qkvb + i*576, Bbuf, nullptr, nullptr, 576, 0);
    // 3. attention -> Abuf
    if (shift) attn_k<true ><<<4096*6, 64, 0, stream>>>(Bbuf, rpb + i*169*6, Abuf);
    else       attn_k<false><<<4096*6, 64, 0, stream>>>(Bbuf, rpb + i*169*6, Abuf);
    // 4. proj gemm + window-reverse scatter residual -> x1
    gemm2_k<1><<<G_P, 256, 0, stream>>>(Abuf, wt + WQ, pb + i*192, nullptr, xin, x1, 192, shift);
    // 5. fused LN2 + FC1 + GELU + FC2 + residual
    mlp_k<<<MROWS/64, 512, 0, stream>>>(x1, n2g + i*192, n2b + i*192,
                                        wt + WQ + WP, f1b + i*768,
                                        wt + WQ + WP + W1, f2b + i*192, xfin);
  }
}